// Round 2
// baseline (1269.022 us; speedup 1.0000x reference)
//
#include <hip/hip_runtime.h>

// Problem constants (fixed by the reference file)
#define M_  512
#define N_  4096
#define D_  128
#define H_  32
#define L_  4096
#define P_  3584

typedef unsigned short u16;
using s16x8 = __attribute__((ext_vector_type(8))) short;
using s16x4 = __attribute__((ext_vector_type(4))) short;
using f32x4 = __attribute__((ext_vector_type(4))) float;

__device__ __forceinline__ u16 f2bf(float f) {
    unsigned u = __builtin_bit_cast(unsigned, f);
    unsigned r = u + 0x7FFFu + ((u >> 16) & 1u);
    return (u16)(r >> 16);
}
__device__ __forceinline__ float bf2f(u16 h) {
    unsigned u = ((unsigned)h) << 16;
    return __builtin_bit_cast(float, u);
}

// async global->LDS, 16B per lane; LDS dest is wave-uniform base + lane*16
__device__ __forceinline__ void g2lds16(const void* g, void* l) {
    __builtin_amdgcn_global_load_lds((const __attribute__((address_space(1))) unsigned int*)g,
                                     (__attribute__((address_space(3))) unsigned int*)l, 16, 0, 0);
}

// ---------------- X fp32 -> hi/lo bf16 ----------------
__global__ __launch_bounds__(256) void k_cvt_hl(const float* __restrict__ in, u16* __restrict__ oh,
                                                u16* __restrict__ ol, int n4) {
    int i = blockIdx.x * 256 + threadIdx.x;
    if (i >= n4) return;
    float4 v = ((const float4*)in)[i];
    ushort4 h, l;
    h.x = f2bf(v.x); l.x = f2bf(v.x - bf2f(h.x));
    h.y = f2bf(v.y); l.y = f2bf(v.y - bf2f(h.y));
    h.z = f2bf(v.z); l.z = f2bf(v.z - bf2f(h.z));
    h.w = f2bf(v.w); l.w = f2bf(v.w - bf2f(h.w));
    ((ushort4*)oh)[i] = h;
    ((ushort4*)ol)[i] = l;
}

// ---------------- one W [4096][4096] fp32 -> transposed hi(/lo) bf16 [4096][4096] ----------------
__global__ __launch_bounds__(256) void k_trans_w2(const float* __restrict__ W, u16* __restrict__ dh,
                                                  u16* __restrict__ dl) {
    __shared__ __align__(16) u16 th[64 * 66];
    __shared__ __align__(16) u16 tl[64 * 66];
    int nt = blockIdx.x >> 6, kt = blockIdx.x & 63;
    int n0 = nt * 64, k0 = kt * 64;
    int t = threadIdx.x;
    int rk = t >> 4, c4 = (t & 15) * 4;
#pragma unroll
    for (int ii = 0; ii < 4; ++ii) {
        int row = rk + ii * 16;
        float4 v = *(const float4*)&W[(size_t)(k0 + row) * N_ + n0 + c4];
        u16* ph = &th[row * 66 + c4];
        u16* pl = &tl[row * 66 + c4];
        ph[0] = f2bf(v.x); pl[0] = f2bf(v.x - bf2f(ph[0]));
        ph[1] = f2bf(v.y); pl[1] = f2bf(v.y - bf2f(ph[1]));
        ph[2] = f2bf(v.z); pl[2] = f2bf(v.z - bf2f(ph[2]));
        ph[3] = f2bf(v.w); pl[3] = f2bf(v.w - bf2f(ph[3]));
    }
    __syncthreads();
    int rn = t >> 2, ks = (t & 3) * 16;
    u16 oh[16], olv[16];
#pragma unroll
    for (int j = 0; j < 16; ++j) { oh[j] = th[(ks + j) * 66 + rn]; olv[j] = tl[(ks + j) * 66 + rn]; }
    uint4* dsth = (uint4*)&dh[(size_t)(n0 + rn) * N_ + k0 + ks];
    dsth[0] = *(uint4*)&oh[0];
    dsth[1] = *(uint4*)&oh[8];
    if (dl) {
        uint4* dstl = (uint4*)&dl[(size_t)(n0 + rn) * N_ + k0 + ks];
        dstl[0] = *(uint4*)&olv[0];
        dstl[1] = *(uint4*)&olv[8];
    }
}

// ---------------- cache_K fp32 -> K hi/lo bf16 (l < P region) ----------------
__global__ __launch_bounds__(256) void k_cvt_cacheK_hl(const float* __restrict__ cK, u16* __restrict__ Kh,
                                                       u16* __restrict__ Kl) {
    int i = blockIdx.x * 256 + threadIdx.x;     // float4 index within [H][P][D]
    const int per_h = P_ * D_ / 4;
    if (i >= H_ * per_h) return;
    int h = i / per_h, r = i - h * per_h;
    size_t off4 = (size_t)h * (L_ * D_ / 4) + r;
    float4 v = ((const float4*)cK)[off4];
    ushort4 oh, ol;
    oh.x = f2bf(v.x); ol.x = f2bf(v.x - bf2f(oh.x));
    oh.y = f2bf(v.y); ol.y = f2bf(v.y - bf2f(oh.y));
    oh.z = f2bf(v.z); ol.z = f2bf(v.z - bf2f(oh.z));
    oh.w = f2bf(v.w); ol.w = f2bf(v.w - bf2f(oh.w));
    ((ushort4*)Kh)[off4] = oh;
    ((ushort4*)Kl)[off4] = ol;
}

// ---------------- cache_V fp32 [h][l<P][d] -> Vt bf16 [h][d][l] ----------------
__global__ __launch_bounds__(256) void k_trans_vc(const float* __restrict__ cV, u16* __restrict__ Vt) {
    __shared__ __align__(16) u16 tile[64 * 66];
    int bi = blockIdx.x;            // h*112 + lt*2 + dt
    int h = bi / 112, r = bi % 112;
    int lt = r >> 1, dt = r & 1;
    int l0 = lt * 64, d0 = dt * 64;
    int t = threadIdx.x;
    int rl = t >> 4, c4 = (t & 15) * 4;
#pragma unroll
    for (int ii = 0; ii < 4; ++ii) {
        int row = rl + ii * 16;
        float4 v = *(const float4*)&cV[((size_t)h * L_ + l0 + row) * D_ + d0 + c4];
        u16* p = &tile[row * 66 + c4];
        p[0] = f2bf(v.x); p[1] = f2bf(v.y); p[2] = f2bf(v.z); p[3] = f2bf(v.w);
    }
    __syncthreads();
    int rd = t >> 2, ls = (t & 3) * 16;
    u16 o[16];
#pragma unroll
    for (int j = 0; j < 16; ++j) o[j] = tile[(ls + j) * 66 + rd];
    uint4* dst = (uint4*)&Vt[((size_t)h * D_ + d0 + rd) * L_ + l0 + ls];
    dst[0] = *(uint4*)&o[0];
    dst[1] = *(uint4*)&o[8];
}

// ---------------- v_tmp bf16 [m][h*128+d] -> Vt bf16 [h][d][P+m] ----------------
__global__ __launch_bounds__(256) void k_trans_vn(const u16* __restrict__ v_tmp, u16* __restrict__ Vt) {
    __shared__ __align__(16) u16 tile[64 * 66];
    int bi = blockIdx.x;            // h*16 + mt*2 + dt
    int h = bi >> 4, r = bi & 15;
    int mt = r >> 1, dt = r & 1;
    int m0 = mt * 64, d0 = dt * 64;
    int t = threadIdx.x;
    int rm = t >> 4, c4 = (t & 15) * 4;
#pragma unroll
    for (int ii = 0; ii < 4; ++ii) {
        int row = rm + ii * 16;
        ushort4 v = *(const ushort4*)&v_tmp[((size_t)(m0 + row)) * N_ + h * D_ + d0 + c4];
        u16* p = &tile[row * 66 + c4];
        p[0] = v.x; p[1] = v.y; p[2] = v.z; p[3] = v.w;
    }
    __syncthreads();
    int rd = t >> 2, ms = (t & 3) * 16;
    u16 o[16];
#pragma unroll
    for (int j = 0; j < 16; ++j) o[j] = tile[(ms + j) * 66 + rd];
    uint4* dst = (uint4*)&Vt[((size_t)h * D_ + d0 + rd) * L_ + P_ + m0 + ms];
    dst[0] = *(uint4*)&o[0];
    dst[1] = *(uint4*)&o[8];
}

// ---------------- split-precision QK projection GEMM ----------------
// C[512][8192] = (Xh+Xl) @ (Wth+Wtl)^T via 3-term MFMA. BM=64, BN=128, BK=32.
// nt<32 -> q head nt ; nt>=32 -> new K rows head nt-32. Outputs stored hi/lo.
__global__ __launch_bounds__(256) void k_gemm_qk(const u16* __restrict__ Xh, const u16* __restrict__ Xl,
                                                 const u16* __restrict__ Wth, const u16* __restrict__ Wtl,
                                                 u16* __restrict__ qh, u16* __restrict__ ql,
                                                 u16* __restrict__ Kh, u16* __restrict__ Kl) {
    __shared__ __align__(16) u16 Ash[64 * 32];
    __shared__ __align__(16) u16 Asl[64 * 32];
    __shared__ __align__(16) u16 Bsh[128 * 32];
    __shared__ __align__(16) u16 Bsl[128 * 32];
    int bi = blockIdx.x;
    int xcd = bi & 7, slot = bi >> 3;       // 64 slots/xcd
    int mt = slot & 7, nt = xcd * 8 + (slot >> 3);
    int m0 = mt * 64, n0 = nt * 128;
    int tid = threadIdx.x, w = tid >> 6, lane = tid & 63;
    int wm = w >> 1, wn = w & 1;
    int lane16 = lane & 15, quad = lane >> 4;
    f32x4 acc[2][4] = {};

    for (int kt = 0; kt < 128; ++kt) {
        int k0 = kt * 32;
#pragma unroll
        for (int i = 0; i < 6; ++i) {
            int c = w * 6 + i;      // 0..23
            if (c < 4)
                g2lds16(Xh + (size_t)(m0 + c * 16 + lane16) * N_ + k0 + quad * 8, &Ash[c * 512]);
            else if (c < 8)
                g2lds16(Xl + (size_t)(m0 + (c - 4) * 16 + lane16) * N_ + k0 + quad * 8, &Asl[(c - 4) * 512]);
            else if (c < 16)
                g2lds16(Wth + (size_t)(n0 + (c - 8) * 16 + lane16) * N_ + k0 + quad * 8, &Bsh[(c - 8) * 512]);
            else
                g2lds16(Wtl + (size_t)(n0 + (c - 16) * 16 + lane16) * N_ + k0 + quad * 8, &Bsl[(c - 16) * 512]);
        }
        __syncthreads();
        s16x8 ah[2], al[2], bh[4], bl[4];
#pragma unroll
        for (int mi = 0; mi < 2; ++mi) {
            ah[mi] = *(const s16x8*)&Ash[((wm * 2 + mi) * 64 + lane) * 8];
            al[mi] = *(const s16x8*)&Asl[((wm * 2 + mi) * 64 + lane) * 8];
        }
#pragma unroll
        for (int ni = 0; ni < 4; ++ni) {
            bh[ni] = *(const s16x8*)&Bsh[((wn * 4 + ni) * 64 + lane) * 8];
            bl[ni] = *(const s16x8*)&Bsl[((wn * 4 + ni) * 64 + lane) * 8];
        }
#pragma unroll
        for (int mi = 0; mi < 2; ++mi)
#pragma unroll
            for (int ni = 0; ni < 4; ++ni) {
                acc[mi][ni] = __builtin_amdgcn_mfma_f32_16x16x32_bf16(ah[mi], bh[ni], acc[mi][ni], 0, 0, 0);
                acc[mi][ni] = __builtin_amdgcn_mfma_f32_16x16x32_bf16(al[mi], bh[ni], acc[mi][ni], 0, 0, 0);
                acc[mi][ni] = __builtin_amdgcn_mfma_f32_16x16x32_bf16(ah[mi], bl[ni], acc[mi][ni], 0, 0, 0);
            }
        __syncthreads();
    }

    int head = nt & 31;
    bool isq = nt < 32;
#pragma unroll
    for (int mi = 0; mi < 2; ++mi)
#pragma unroll
        for (int ni = 0; ni < 4; ++ni)
#pragma unroll
            for (int rr = 0; rr < 4; ++rr) {
                int m = m0 + wm * 32 + mi * 16 + quad * 4 + rr;
                int d = wn * 64 + ni * 16 + lane16;
                float v = acc[mi][ni][rr];
                u16 h = f2bf(v), lo = f2bf(v - bf2f(h));
                if (isq) {
                    qh[((size_t)head * M_ + m) * D_ + d] = h;
                    ql[((size_t)head * M_ + m) * D_ + d] = lo;
                } else {
                    Kh[((size_t)head * L_ + P_ + m) * D_ + d] = h;
                    Kl[((size_t)head * L_ + P_ + m) * D_ + d] = lo;
                }
            }
}

// ---------------- single-precision V projection GEMM ----------------
__global__ __launch_bounds__(256) void k_gemm_v(const u16* __restrict__ Xh, const u16* __restrict__ Wth,
                                                u16* __restrict__ v_tmp) {
    __shared__ __align__(16) u16 Ash[64 * 32];
    __shared__ __align__(16) u16 Bsh[128 * 32];
    int bi = blockIdx.x;
    int xcd = bi & 7, slot = bi >> 3;       // 32 slots/xcd
    int mt = slot & 7, nt = xcd * 4 + (slot >> 3);
    int m0 = mt * 64, n0 = nt * 128;
    int tid = threadIdx.x, w = tid >> 6, lane = tid & 63;
    int wm = w >> 1, wn = w & 1;
    int lane16 = lane & 15, quad = lane >> 4;
    f32x4 acc[2][4] = {};

    for (int kt = 0; kt < 128; ++kt) {
        int k0 = kt * 32;
#pragma unroll
        for (int i = 0; i < 3; ++i) {
            int c = w * 3 + i;      // 0..11
            if (c < 4)
                g2lds16(Xh + (size_t)(m0 + c * 16 + lane16) * N_ + k0 + quad * 8, &Ash[c * 512]);
            else
                g2lds16(Wth + (size_t)(n0 + (c - 4) * 16 + lane16) * N_ + k0 + quad * 8, &Bsh[(c - 4) * 512]);
        }
        __syncthreads();
        s16x8 ah[2], bh[4];
#pragma unroll
        for (int mi = 0; mi < 2; ++mi) ah[mi] = *(const s16x8*)&Ash[((wm * 2 + mi) * 64 + lane) * 8];
#pragma unroll
        for (int ni = 0; ni < 4; ++ni) bh[ni] = *(const s16x8*)&Bsh[((wn * 4 + ni) * 64 + lane) * 8];
#pragma unroll
        for (int mi = 0; mi < 2; ++mi)
#pragma unroll
            for (int ni = 0; ni < 4; ++ni)
                acc[mi][ni] = __builtin_amdgcn_mfma_f32_16x16x32_bf16(ah[mi], bh[ni], acc[mi][ni], 0, 0, 0);
        __syncthreads();
    }

    int head = nt;
#pragma unroll
    for (int mi = 0; mi < 2; ++mi)
#pragma unroll
        for (int ni = 0; ni < 4; ++ni)
#pragma unroll
            for (int rr = 0; rr < 4; ++rr) {
                int m = m0 + wm * 32 + mi * 16 + quad * 4 + rr;
                int d = wn * 64 + ni * 16 + lane16;
                v_tmp[(size_t)m * N_ + head * D_ + d] = f2bf(acc[mi][ni][rr]);
            }
}

// ---------------- fused attention, split-precision QK^T ----------------
__global__ __launch_bounds__(256) void k_attn(const u16* __restrict__ q_h, const u16* __restrict__ q_l,
                                              const u16* __restrict__ Kh, const u16* __restrict__ Kl,
                                              const u16* __restrict__ Vt, const float* __restrict__ noise,
                                              float* __restrict__ out0, float* __restrict__ out1,
                                              float* __restrict__ S2ws) {
    __shared__ __align__(16) u16 Ksh[64 * 128];
    __shared__ __align__(16) u16 Ksl[64 * 128];
    __shared__ __align__(16) u16 Vs[128 * 64];
    __shared__ __align__(16) u16 wlds[4][16 * 68];
    int bi = blockIdx.x;
    int h = bi & 31, mt = bi >> 5;
    int m0 = mt * 64;
    int tid = threadIdx.x;
    int w = tid >> 6, lane = tid & 63;
    int lane16 = lane & 15, quad = lane >> 4;
    int rm0 = w * 16;

    s16x8 qfh[4], qfl[4];
    {
        const u16* qp = q_h + ((size_t)h * M_ + m0 + rm0 + lane16) * D_ + quad * 8;
        const u16* qp2 = q_l + ((size_t)h * M_ + m0 + rm0 + lane16) * D_ + quad * 8;
#pragma unroll
        for (int kk = 0; kk < 4; ++kk) {
            qfh[kk] = *(const s16x8*)(qp + kk * 32);
            qfl[kk] = *(const s16x8*)(qp2 + kk * 32);
        }
    }
    float acc1[4] = {0.f, 0.f, 0.f, 0.f};
    float acc2[4] = {0.f, 0.f, 0.f, 0.f};
    f32x4 Oacc[8] = {};

    const float* noise_row = noise + ((size_t)h * M_ + m0 + rm0) * L_;
    float* out1_row = out1 + ((size_t)h * M_ + m0 + rm0) * L_;

    for (int it = 0; it < 64; ++it) {
        int l0 = it * 64;
#pragma unroll
        for (int i = 0; i < 12; ++i) {
            int c = w * 12 + i;     // 0..47
            if (c < 16) {
                int ni = c >> 2, kk = c & 3;
                g2lds16(Kh + ((size_t)h * L_ + l0 + ni * 16 + lane16) * D_ + kk * 32 + quad * 8,
                        &Ksh[c * 512]);
            } else if (c < 32) {
                int cc = c - 16, ni = cc >> 2, kk = cc & 3;
                g2lds16(Kl + ((size_t)h * L_ + l0 + ni * 16 + lane16) * D_ + kk * 32 + quad * 8,
                        &Ksl[cc * 512]);
            } else {
                int cc = c - 32, dt = cc >> 1, kk2 = cc & 1;
                g2lds16(Vt + ((size_t)h * D_ + dt * 16 + lane16) * L_ + l0 + kk2 * 32 + quad * 8,
                        &Vs[cc * 512]);
            }
        }
        float nz[4][4];
#pragma unroll
        for (int ni = 0; ni < 4; ++ni)
#pragma unroll
            for (int rr = 0; rr < 4; ++rr)
                nz[ni][rr] = noise_row[(size_t)(quad * 4 + rr) * L_ + l0 + ni * 16 + lane16];
        __syncthreads();

#pragma unroll
        for (int ni = 0; ni < 4; ++ni) {
            f32x4 s4 = {};
#pragma unroll
            for (int kk = 0; kk < 4; ++kk) {
                s16x8 kfh = *(const s16x8*)&Ksh[((ni * 4 + kk) * 64 + lane) * 8];
                s16x8 kfl = *(const s16x8*)&Ksl[((ni * 4 + kk) * 64 + lane) * 8];
                s4 = __builtin_amdgcn_mfma_f32_16x16x32_bf16(qfh[kk], kfh, s4, 0, 0, 0);
                s4 = __builtin_amdgcn_mfma_f32_16x16x32_bf16(qfl[kk], kfh, s4, 0, 0, 0);
                s4 = __builtin_amdgcn_mfma_f32_16x16x32_bf16(qfh[kk], kfl, s4, 0, 0, 0);
            }
#pragma unroll
            for (int rr = 0; rr < 4; ++rr) {
                float e1 = __expf(s4[rr]);
                float e2 = __expf((s4[rr] + nz[ni][rr]) * 0.66666666666f);
                acc1[rr] += e1;
                acc2[rr] += e2;
                out1_row[(size_t)(quad * 4 + rr) * L_ + l0 + ni * 16 + lane16] = e2;
                wlds[w][(quad * 4 + rr) * 68 + ni * 16 + lane16] = f2bf(e1);
            }
        }
#pragma unroll
        for (int kk2 = 0; kk2 < 2; ++kk2) {
            s16x4 wlo = *(const s16x4*)&wlds[w][lane16 * 68 + kk2 * 32 + quad * 8];
            s16x4 whi = *(const s16x4*)&wlds[w][lane16 * 68 + kk2 * 32 + quad * 8 + 4];
            s16x8 wf = __builtin_shufflevector(wlo, whi, 0, 1, 2, 3, 4, 5, 6, 7);
#pragma unroll
            for (int dt = 0; dt < 8; ++dt) {
                s16x8 vf = *(const s16x8*)&Vs[((dt * 2 + kk2) * 64 + lane) * 8];
                Oacc[dt] = __builtin_amdgcn_mfma_f32_16x16x32_bf16(wf, vf, Oacc[dt], 0, 0, 0);
            }
        }
        __syncthreads();
    }

#pragma unroll
    for (int rr = 0; rr < 4; ++rr) {
        float s1 = acc1[rr], s2 = acc2[rr];
#pragma unroll
        for (int mask = 1; mask < 16; mask <<= 1) {
            s1 += __shfl_xor(s1, mask, 64);
            s2 += __shfl_xor(s2, mask, 64);
        }
        float inv1 = 1.0f / s1;
        int m = m0 + rm0 + quad * 4 + rr;
        if (lane16 == 0) S2ws[h * M_ + m] = s2;
#pragma unroll
        for (int dt = 0; dt < 8; ++dt)
            out0[(size_t)m * N_ + h * D_ + dt * 16 + lane16] = Oacc[dt][rr] * inv1;
    }
}

// ---------------- normalize perturb_out rows by 1/S2 ----------------
__global__ __launch_bounds__(256) void k_norm(float* __restrict__ out1, const float* __restrict__ S2ws) {
    int row = blockIdx.x;               // h*512 + m
    float inv = 1.0f / S2ws[row];
    float4* p = (float4*)(out1 + (size_t)row * L_);
    int t = threadIdx.x;
#pragma unroll
    for (int i = 0; i < 4; ++i) {
        float4 v = p[t + i * 256];
        v.x *= inv; v.y *= inv; v.z *= inv; v.w *= inv;
        p[t + i * 256] = v;
    }
}

extern "C" void kernel_launch(void* const* d_in, const int* in_sizes, int n_in,
                              void* d_out, int out_size, void* d_ws, size_t ws_size,
                              hipStream_t stream) {
    const float* X     = (const float*)d_in[0];
    const float* Wq    = (const float*)d_in[1];
    const float* Wk    = (const float*)d_in[2];
    const float* Wv    = (const float*)d_in[3];
    const float* noise = (const float*)d_in[4];
    const float* cK    = (const float*)d_in[5];
    const float* cV    = (const float*)d_in[6];

    float* out0 = (float*)d_out;                       // [512][4096]
    float* out1 = out0 + (size_t)M_ * N_;              // [32][512][4096]

    // workspace partition (~244 MiB)
    char* ws = (char*)d_ws;
    const size_t MiB = 1 << 20;
    u16*   Xh   = (u16*)(ws);                   //   4 MiB [512][4096]
    u16*   Xl   = (u16*)(ws + 4 * MiB);         //   4 MiB
    u16*   Wth  = (u16*)(ws + 8 * MiB);         //  64 MiB [8192][4096] (Q^T,K^T hi; later Wv^T hi in first 32)
    u16*   Wtl  = (u16*)(ws + 72 * MiB);        //  64 MiB (Q^T,K^T lo)
    u16*   q_h  = (u16*)(ws + 136 * MiB);       //   4 MiB [32][512][128]
    u16*   q_l  = (u16*)(ws + 140 * MiB);       //   4 MiB
    u16*   K_h  = (u16*)(ws + 144 * MiB);       //  32 MiB [32][4096][128]
    u16*   K_l  = (u16*)(ws + 176 * MiB);       //  32 MiB
    u16*   Vt   = (u16*)(ws + 208 * MiB);       //  32 MiB [32][128][4096]
    u16*   v_tmp= (u16*)(ws + 240 * MiB);       //   4 MiB [512][4096]
    float* S2ws = (float*)(ws + 244 * MiB);     //  64 KiB [32*512]

    k_cvt_hl<<<2048, 256, 0, stream>>>(X, Xh, Xl, M_ * N_ / 4);
    k_trans_w2<<<4096, 256, 0, stream>>>(Wq, Wth, Wtl);
    k_trans_w2<<<4096, 256, 0, stream>>>(Wk, Wth + (size_t)N_ * N_, Wtl + (size_t)N_ * N_);
    k_cvt_cacheK_hl<<<14336, 256, 0, stream>>>(cK, K_h, K_l);
    k_trans_vc<<<3584, 256, 0, stream>>>(cV, Vt);
    k_gemm_qk<<<512, 256, 0, stream>>>(Xh, Xl, Wth, Wtl, q_h, q_l, K_h, K_l);
    // reuse Wth's first 32 MiB for Wv^T (stream order guarantees gemm_qk is done)
    k_trans_w2<<<4096, 256, 0, stream>>>(Wv, Wth, (u16*)nullptr);
    k_gemm_v<<<256, 256, 0, stream>>>(Xh, Wth, v_tmp);
    k_trans_vn<<<512, 256, 0, stream>>>(v_tmp, Vt);
    k_attn<<<256, 256, 0, stream>>>(q_h, q_l, K_h, K_l, Vt, noise, out0, out1, S2ws);
    k_norm<<<16384, 256, 0, stream>>>(out1, S2ws);
}